// Round 3
// baseline (1126.704 us; speedup 1.0000x reference)
//
#include <hip/hip_runtime.h>

#define NROW 16384
#define DIM  64
#define TSTEPS 8
#define MAXST 12
#define NBLK 256
#define TPB  512
#define NWAVE (TPB/64)
#define RPB  (NROW/NBLK)      /* 64 rows per block */
#define RPW  (RPB/NWAVE)      /* 8 rows per wave  */
#define MAXSID 96             /* > 7 segments * 12 steps */

#define ODE_RTOL 0.01f
#define ODE_ATOL 0.001f

// ---- dopri5 tableau (double-folded at compile time, rounded to f32 like jnp) ----
#define C21 ((float)(0.2))
#define C31 ((float)(3.0/40.0))
#define C32 ((float)(9.0/40.0))
#define C41 ((float)(44.0/45.0))
#define C42 ((float)(-56.0/15.0))
#define C43 ((float)(32.0/9.0))
#define C51 ((float)(19372.0/6561.0))
#define C52 ((float)(-25360.0/2187.0))
#define C53 ((float)(64448.0/6561.0))
#define C54 ((float)(-212.0/729.0))
#define C61 ((float)(9017.0/3168.0))
#define C62 ((float)(-355.0/33.0))
#define C63 ((float)(46732.0/5247.0))
#define C64 ((float)(49.0/176.0))
#define C65 ((float)(-5103.0/18656.0))
#define B1  ((float)(35.0/384.0))
#define B3  ((float)(500.0/1113.0))
#define B4  ((float)(125.0/192.0))
#define B5  ((float)(-2187.0/6784.0))
#define B6  ((float)(11.0/84.0))
#define E1  ((float)(35.0/384.0 - 5179.0/57600.0))
#define E3  ((float)(500.0/1113.0 - 7571.0/16695.0))
#define E4  ((float)(125.0/192.0 - 393.0/640.0))
#define E5  ((float)(-2187.0/6784.0 + 92097.0/339200.0))
#define E6  ((float)(11.0/84.0 - 187.0/2100.0))
#define E7  ((float)(-1.0/40.0))

// Grid-barrier state in module globals (NOT d_ws — d_ws size is unverified and
// the harness poisons it; these are zero-init at load and the barrier protocol
// below self-resets every used slot to zero before kernel exit, so every call
// starts from the same state). One slot per active step (sid), used once/call.
__device__ unsigned int g_cnt [MAXSID];          // arrival counters
__device__ unsigned int g_flag[MAXSID];          // "total published" flags
__device__ unsigned int g_done[MAXSID];          // pass-through counters (for reset)
__device__ float        g_tot [MAXSID];          // published deterministic totals
__device__ float        g_part[MAXSID * NBLK];   // per-block partial sums

// dot of a 64-float LDS row (same address all lanes -> broadcast reads) with a
// per-lane register-resident weight column. Fully unrolled so wc[] stays in VGPRs.
__device__ __forceinline__ float dot64(const float* src, const float* wc) {
  float u0 = 0.f, u1 = 0.f, u2 = 0.f, u3 = 0.f;
#pragma unroll
  for (int i = 0; i < DIM; i += 4) {
    float4 z = *(const float4*)(src + i);   // 16B-aligned LDS broadcast
    u0 = fmaf(z.x, wc[i + 0], u0);
    u1 = fmaf(z.y, wc[i + 1], u1);
    u2 = fmaf(z.z, wc[i + 2], u2);
    u3 = fmaf(z.w, wc[i + 3], u3);
  }
  return (u0 + u1) + (u2 + u3);
}

// One evaluation of f for one row: zsrc (LDS row, wave-written) -> returns k_lane.
__device__ __forceinline__ float evalRow(const float* zsrc, float* aw,
                                         const float* w1c, const float* w2c,
                                         float b1v, float b2v, int lane) {
  float u = dot64(zsrc, w1c) + b1v;
  float a = tanhf(u);
  aw[lane] = a;
  return dot64(aw, w2c) + b2v;
}

__global__ __launch_bounds__(TPB, 2)
void ode_dopri5_kernel(const float* __restrict__ vt, const float* __restrict__ y0,
                       const float* __restrict__ W1, const float* __restrict__ b1,
                       const float* __restrict__ W2, const float* __restrict__ b2,
                       float* __restrict__ out) {
  // Row-state resident in LDS for the whole integration.
  // Slots: y, k1..k6. k2 slot doubles as y5 after stage 6 (b2=e2=0);
  // k7 lands in k3 slot after the err pass. FSAL: k1 <- k7 on accept.
  __shared__ __align__(16) float Sbuf[7][RPB][DIM];      // 112 KB
  __shared__ __align__(16) float zrow[NWAVE][DIM];       // per-wave stage-arg scratch
  __shared__ __align__(16) float arow[NWAVE][DIM];       // per-wave activation scratch
  __shared__ float redbuf[NWAVE];
  __shared__ float bcast[1];

  const int tid  = threadIdx.x;
  const int lane = tid & 63;
  const int wv   = tid >> 6;
  const int row0 = blockIdx.x * RPB;

  // W columns persistent in VGPRs: lane j holds W1[:,j], W2[:,j] (128 VGPRs).
  float w1c[DIM], w2c[DIM];
#pragma unroll
  for (int i = 0; i < DIM; ++i) {
    w1c[i] = W1[i * DIM + lane];
    w2c[i] = W2[i * DIM + lane];
  }
  const float b1v = b1[lane];
  const float b2v = b2[lane];

  typedef float RowArr[DIM];
  RowArr* py  = Sbuf[0];
  RowArr* pk1 = Sbuf[1];
  RowArr* pk2 = Sbuf[2];
  RowArr* pk3 = Sbuf[3];
  RowArr* pk4 = Sbuf[4];
  RowArr* pk5 = Sbuf[5];
  RowArr* pk6 = Sbuf[6];

  float* aw = &arow[wv][0];
  float* zw = &zrow[wv][0];

  // Load y0 into LDS; emit ys[0] = y0.
  for (int rr = 0; rr < RPW; ++rr) {
    int r = wv * RPW + rr;
    float yv = y0[(size_t)(row0 + r) * DIM + lane];
    py[r][lane] = yv;
    out[(size_t)(row0 + r) * DIM + lane] = yv;
  }

  // Initial k1 = f(y0). (FSAL carries it across all subsequent steps/segments.)
  for (int rr = 0; rr < RPW; ++rr) {
    int r = wv * RPW + rr;
    pk1[r][lane] = evalRow(&py[r][0], aw, w1c, w2c, b1v, b2v, lane);
  }

  float h  = (vt[1] - vt[0]) * 0.1f;
  int sid  = 0;   // active-step counter; identical across blocks (decisions are global)

  for (int seg = 0; seg < TSTEPS - 1; ++seg) {
    const float t1 = vt[seg + 1];
    float t = vt[seg];

    for (int st = 0; st < MAXST; ++st) {
      float rem = t1 - t;
      if (!(rem > 1e-9f)) break;          // inactive steps are exact no-ops in the ref
      float htry = fminf(h, rem);         // rem > 1e-9 => max(rem,1e-9)=rem

      // ---- stage 2 -> k2 ----
      for (int rr = 0; rr < RPW; ++rr) {
        int r = wv * RPW + rr;
        float yv = py[r][lane], k1v = pk1[r][lane];
        zw[lane] = fmaf(htry, C21 * k1v, yv);
        pk2[r][lane] = evalRow(zw, aw, w1c, w2c, b1v, b2v, lane);
      }
      // ---- stage 3 -> k3 ----
      for (int rr = 0; rr < RPW; ++rr) {
        int r = wv * RPW + rr;
        float yv = py[r][lane], k1v = pk1[r][lane], k2v = pk2[r][lane];
        float c = fmaf(C32, k2v, C31 * k1v);
        zw[lane] = fmaf(htry, c, yv);
        pk3[r][lane] = evalRow(zw, aw, w1c, w2c, b1v, b2v, lane);
      }
      // ---- stage 4 -> k4 ----
      for (int rr = 0; rr < RPW; ++rr) {
        int r = wv * RPW + rr;
        float yv = py[r][lane], k1v = pk1[r][lane], k2v = pk2[r][lane], k3v = pk3[r][lane];
        float c = C41 * k1v; c = fmaf(C42, k2v, c); c = fmaf(C43, k3v, c);
        zw[lane] = fmaf(htry, c, yv);
        pk4[r][lane] = evalRow(zw, aw, w1c, w2c, b1v, b2v, lane);
      }
      // ---- stage 5 -> k5 ----
      for (int rr = 0; rr < RPW; ++rr) {
        int r = wv * RPW + rr;
        float yv = py[r][lane], k1v = pk1[r][lane], k2v = pk2[r][lane];
        float k3v = pk3[r][lane], k4v = pk4[r][lane];
        float c = C51 * k1v; c = fmaf(C52, k2v, c); c = fmaf(C53, k3v, c); c = fmaf(C54, k4v, c);
        zw[lane] = fmaf(htry, c, yv);
        pk5[r][lane] = evalRow(zw, aw, w1c, w2c, b1v, b2v, lane);
      }
      // ---- stage 6 -> k6 (last use of k2) ----
      for (int rr = 0; rr < RPW; ++rr) {
        int r = wv * RPW + rr;
        float yv = py[r][lane], k1v = pk1[r][lane], k2v = pk2[r][lane];
        float k3v = pk3[r][lane], k4v = pk4[r][lane], k5v = pk5[r][lane];
        float c = C61 * k1v; c = fmaf(C62, k2v, c); c = fmaf(C63, k3v, c);
        c = fmaf(C64, k4v, c); c = fmaf(C65, k5v, c);
        zw[lane] = fmaf(htry, c, yv);
        pk6[r][lane] = evalRow(zw, aw, w1c, w2c, b1v, b2v, lane);
      }
      // ---- y5 -> k2 slot (elementwise) ----
      for (int rr = 0; rr < RPW; ++rr) {
        int r = wv * RPW + rr;
        float yv = py[r][lane], k1v = pk1[r][lane];
        float k3v = pk3[r][lane], k4v = pk4[r][lane], k5v = pk5[r][lane], k6v = pk6[r][lane];
        float c = B1 * k1v; c = fmaf(B3, k3v, c); c = fmaf(B4, k4v, c);
        c = fmaf(B5, k5v, c); c = fmaf(B6, k6v, c);
        pk2[r][lane] = fmaf(htry, c, yv);
      }
      // ---- k7 = f(y5), fused err accumulation; k7 -> k3 slot ----
      float acc = 0.f;
      for (int rr = 0; rr < RPW; ++rr) {
        int r = wv * RPW + rr;
        float k7 = evalRow(&pk2[r][0], aw, w1c, w2c, b1v, b2v, lane);
        float yv = py[r][lane], y5v = pk2[r][lane];
        float k1v = pk1[r][lane], k3v = pk3[r][lane], k4v = pk4[r][lane];
        float k5v = pk5[r][lane], k6v = pk6[r][lane];
        float e = E1 * k1v; e = fmaf(E3, k3v, e); e = fmaf(E4, k4v, e);
        e = fmaf(E5, k5v, e); e = fmaf(E6, k6v, e); e = fmaf(E7, k7, e);
        e *= htry;
        float sc = fmaf(ODE_RTOL, fmaxf(fabsf(yv), fabsf(y5v)), ODE_ATOL);
        float q = e / sc;
        acc = fmaf(q, q, acc);
        pk3[r][lane] = k7;
      }

      // ---- deterministic global err reduction + self-resetting grid barrier ----
      // wave reduce (fixed tree), block reduce (fixed order), device reduce:
      // block 0 alone sums the 256 partials in fixed order => bit-identical
      // total on every call, every block. All cross-block data moves via
      // device-scope atomics (cross-XCD safe).
#pragma unroll
      for (int off = 32; off > 0; off >>= 1) acc += __shfl_xor(acc, off, 64);
      if (lane == 0) redbuf[wv] = acc;
      __syncthreads();
      if (tid == 0) {
        float bsum = 0.f;
        for (int w = 0; w < NWAVE; ++w) bsum += redbuf[w];
        atomicExch(&g_part[sid * NBLK + (int)blockIdx.x], bsum);
        __threadfence();
        atomicAdd(&g_cnt[sid], 1u);
        float tot;
        if (blockIdx.x == 0) {
          while (atomicAdd(&g_cnt[sid], 0u) < (unsigned)NBLK)
            __builtin_amdgcn_s_sleep(8);
          __threadfence();
          tot = 0.f;
          for (int b = 0; b < NBLK; ++b)
            tot += atomicAdd(&g_part[sid * NBLK + b], 0.0f);
          atomicExch(&g_tot[sid], tot);
          __threadfence();
          atomicExch(&g_flag[sid], 1u);
        } else {
          while (atomicAdd(&g_flag[sid], 0u) == 0u)
            __builtin_amdgcn_s_sleep(8);
          __threadfence();
          tot = atomicAdd(&g_tot[sid], 0.0f);
        }
        // pass-through count; the LAST block through resets the slot to zero so
        // the next call starts from all-zero globals (g_part/g_tot are
        // overwritten-before-read next call and need no reset).
        __threadfence();
        unsigned d = atomicAdd(&g_done[sid], 1u);
        if (d == (unsigned)(NBLK - 1)) {
          atomicExch(&g_cnt[sid], 0u);
          atomicExch(&g_flag[sid], 0u);
          atomicExch(&g_done[sid], 0u);
        }
        bcast[0] = tot;
      }
      __syncthreads();
      float tot = bcast[0];

      float err_norm = fmaxf(sqrtf(tot * (1.0f / (float)(NROW * DIM))), 1e-10f);
      bool accept  = (err_norm <= 1.0f);
      float factor = fminf(fmaxf(0.9f * powf(err_norm, -0.2f), 0.2f), 10.0f);
      if (accept) {
        t = t + htry;
        RowArr* tmp = py;  py  = pk2; pk2 = tmp;    // y  <- y5
        tmp = pk1; pk1 = pk3; pk3 = tmp;            // k1 <- k7 (FSAL)
      }
      h = htry * factor;
      ++sid;
    }

    // Emit ys[seg+1].
    for (int rr = 0; rr < RPW; ++rr) {
      int r = wv * RPW + rr;
      out[((size_t)(seg + 1) * NROW + row0 + r) * DIM + lane] = py[r][lane];
    }
  }
}

extern "C" void kernel_launch(void* const* d_in, const int* in_sizes, int n_in,
                              void* d_out, int out_size, void* d_ws, size_t ws_size,
                              hipStream_t stream) {
  const float* vt = (const float*)d_in[0];
  const float* y0 = (const float*)d_in[1];
  const float* W1 = (const float*)d_in[2];
  const float* b1 = (const float*)d_in[3];
  const float* W2 = (const float*)d_in[4];
  const float* b2 = (const float*)d_in[5];
  float* out = (float*)d_out;
  (void)d_ws; (void)ws_size;   // deliberately unused: barrier state lives in
                               // self-resetting __device__ globals

  hipLaunchKernelGGL(ode_dopri5_kernel, dim3(NBLK), dim3(TPB), 0, stream,
                     vt, y0, W1, b1, W2, b2, out);
}

// Round 5
// 406.110 us; speedup vs baseline: 2.7744x; 2.7744x over previous
//
#include <hip/hip_runtime.h>

#define NROW 16384
#define DIM  64
#define TSTEPS 8
#define MAXST 12
#define NBLK 512              /* 512 blocks x 32 rows; 2 blocks/CU co-resident */
#define TPB  512
#define RPB  32               /* rows per block */
#define MAXSID 96

#define ODE_RTOL 0.01f
#define ODE_ATOL 0.001f

#define C21 ((float)(0.2))
#define C31 ((float)(3.0/40.0))
#define C32 ((float)(9.0/40.0))
#define C41 ((float)(44.0/45.0))
#define C42 ((float)(-56.0/15.0))
#define C43 ((float)(32.0/9.0))
#define C51 ((float)(19372.0/6561.0))
#define C52 ((float)(-25360.0/2187.0))
#define C53 ((float)(64448.0/6561.0))
#define C54 ((float)(-212.0/729.0))
#define C61 ((float)(9017.0/3168.0))
#define C62 ((float)(-355.0/33.0))
#define C63 ((float)(46732.0/5247.0))
#define C64 ((float)(49.0/176.0))
#define C65 ((float)(-5103.0/18656.0))
#define B1  ((float)(35.0/384.0))
#define B3  ((float)(500.0/1113.0))
#define B4  ((float)(125.0/192.0))
#define B5  ((float)(-2187.0/6784.0))
#define B6  ((float)(11.0/84.0))
#define E1  ((float)(35.0/384.0 - 5179.0/57600.0))
#define E3  ((float)(500.0/1113.0 - 7571.0/16695.0))
#define E4  ((float)(125.0/192.0 - 393.0/640.0))
#define E5  ((float)(-2187.0/6784.0 + 92097.0/339200.0))
#define E6  ((float)(11.0/84.0 - 187.0/2100.0))
#define E7  ((float)(-1.0/40.0))

typedef __attribute__((ext_vector_type(8))) short          s8x8;   // 8 bf16 (4 VGPR)
typedef __attribute__((ext_vector_type(8))) unsigned short u16x8;
typedef __attribute__((ext_vector_type(4))) float          f32x4;
#define MFMA16 __builtin_amdgcn_mfma_f32_16x16x32_bf16

// Grid-barrier state in module globals (zero-init at load; the protocol
// self-resets every used slot to zero before kernel exit -> every call starts
// from identical state; d_ws deliberately untouched).
__device__ unsigned int g_cnt [MAXSID];
__device__ unsigned int g_flag[MAXSID];
__device__ unsigned int g_done[MAXSID];
__device__ float        g_tot [MAXSID];
__device__ float        g_part[MAXSID * NBLK];

__device__ __forceinline__ unsigned short bfrn(float x) {   // f32 -> bf16 RNE
  unsigned u = __builtin_bit_cast(unsigned, x);
  u += 0x7FFFu + ((u >> 16) & 1u);
  return (unsigned short)(u >> 16);
}
__device__ __forceinline__ float bf2f(unsigned short h) {
  unsigned u = ((unsigned)h) << 16;
  return __builtin_bit_cast(float, u);
}
// x ~= hi + mid + lo (each bf16); residuals exact in f32 -> ~2^-24 total error
__device__ __forceinline__ void split3(float x, unsigned short& h,
                                       unsigned short& m, unsigned short& lo) {
  h = bfrn(x); float r  = x - bf2f(h);
  m = bfrn(r); float r2 = r - bf2f(m);
  lo = bfrn(r2);
}

__global__ __launch_bounds__(TPB, 4)   // 4 waves/EU -> 2 blocks/CU guaranteed
void ode_dopri5_mfma(const float* __restrict__ vt, const float* __restrict__ y0,
                     const float* __restrict__ W1, const float* __restrict__ b1,
                     const float* __restrict__ W2, const float* __restrict__ b2,
                     float* __restrict__ out) {
  // A-operand fragment buffers (bf16x3 planes) for Z and tanh-activations.
  // Layout: u16 index = ((rt*2+ks)*64 + lane_slot)*8 + (k&7),
  //   lane_slot = (row&15) | (((k>>3)&3)<<4), rt=row>>4, ks=k>>5.
  __shared__ __align__(16) unsigned short ZF [3][2048];
  __shared__ __align__(16) unsigned short AFR[3][2048];
  // W mid/lo planes in B-frag order: u16 idx = ((ct*2+ks)*64 + lane_slot)*8 + (k&7),
  //   lane_slot = (n&15) | (((k>>3)&3)<<4).  (W-hi planes live in VGPRs per wave.)
  __shared__ __align__(16) unsigned short W1M[4096], W1L[4096], W2M[4096], W2L[4096];
  __shared__ float redbuf[8];
  __shared__ float bcast;

  const int tid = threadIdx.x;
  const int l   = tid & 63;
  const int w   = tid >> 6;      // wave 0..7
  const int rt  = w >> 2;        // row-tile 0..1  (16 rows each)
  const int ct  = w & 3;         // col-tile 0..3  (16 cols each)
  const int l15 = l & 15;
  const int lq  = l >> 4;        // 0..3
  const int m0  = rt * 16 + lq * 4;        // first owned row (thread owns q=0..3)
  const int n   = ct * 16 + l15;           // owned column (C-frag col)
  const int row0 = blockIdx.x * RPB;

  // Owned-element fragment write offset (u16 units); +8 per q (row+1).
  const int zoff = ((rt * 2 + (n >> 5)) * 64 + ((m0 & 15) | (((n >> 3) & 3) << 4))) * 8 + (n & 7);
  // Fragment read offsets.
  const int ro0 = ((rt * 2 + 0) * 64 + l) * 8, ro1 = ((rt * 2 + 1) * 64 + l) * 8;
  const int wo0 = ((ct * 2 + 0) * 64 + l) * 8, wo1 = ((ct * 2 + 1) * 64 + l) * 8;

  // ---- one-time W staging ----
  // (a) mid/lo planes -> LDS (thread t covers col n_i, rows 8q_i..8q_i+7)
  {
    const int n_i = tid >> 3, q_i = tid & 7;
    const int slot = ((( n_i >> 4) * 2 + (q_i >> 2)) * 64 + ((n_i & 15) | ((q_i & 3) << 4))) * 8;
    u16x8 m1v, l1v, m2v, l2v;
#pragma unroll
    for (int i = 0; i < 8; ++i) {
      unsigned short h, m, lo;
      split3(W1[(q_i * 8 + i) * 64 + n_i], h, m, lo); m1v[i] = m; l1v[i] = lo;
      split3(W2[(q_i * 8 + i) * 64 + n_i], h, m, lo); m2v[i] = m; l2v[i] = lo;
    }
    *(u16x8*)&W1M[slot] = m1v; *(u16x8*)&W1L[slot] = l1v;
    *(u16x8*)&W2M[slot] = m2v; *(u16x8*)&W2L[slot] = l2v;
  }
  // (b) hi planes -> VGPR B-frags for this wave's column tile
  s8x8 w1h[2], w2h[2];
#pragma unroll
  for (int ks = 0; ks < 2; ++ks) {
    u16x8 t1, t2;
#pragma unroll
    for (int i = 0; i < 8; ++i) {
      t1[i] = bfrn(W1[(ks * 32 + lq * 8 + i) * 64 + n]);
      t2[i] = bfrn(W2[(ks * 32 + lq * 8 + i) * 64 + n]);
    }
    w1h[ks] = __builtin_bit_cast(s8x8, t1);
    w2h[ks] = __builtin_bit_cast(s8x8, t2);
  }
  const float b1c = b1[n];
  const float b2c = b2[n];

  // ---- register-resident state (4 owned elements each) ----
  float y[4], k1[4], k2[4], k3[4], k4[4], k5[4], k6[4], k7[4], y5[4], z[4];

  // f-eval: zv[4] (owner layout) -> kout[4]; 2 block barriers.
  auto EVAL = [&](const float* zv, float* kout) {
#pragma unroll
    for (int q = 0; q < 4; ++q) {
      unsigned short h, m, lo; split3(zv[q], h, m, lo);
      ZF[0][zoff + 8 * q] = h; ZF[1][zoff + 8 * q] = m; ZF[2][zoff + 8 * q] = lo;
    }
    __syncthreads();
    f32x4 acc = {b1c, b1c, b1c, b1c};
#pragma unroll
    for (int ks = 0; ks < 2; ++ks) {
      const int ro = ks ? ro1 : ro0, wo = ks ? wo1 : wo0;
      s8x8 zh = *(const s8x8*)&ZF[0][ro];
      s8x8 zm = *(const s8x8*)&ZF[1][ro];
      s8x8 zl = *(const s8x8*)&ZF[2][ro];
      s8x8 wm = *(const s8x8*)&W1M[wo];
      s8x8 wl = *(const s8x8*)&W1L[wo];
      acc = MFMA16(zh, w1h[ks], acc, 0, 0, 0);
      acc = MFMA16(zm, w1h[ks], acc, 0, 0, 0);
      acc = MFMA16(zl, w1h[ks], acc, 0, 0, 0);
      acc = MFMA16(zh, wm, acc, 0, 0, 0);
      acc = MFMA16(zm, wm, acc, 0, 0, 0);
      acc = MFMA16(zh, wl, acc, 0, 0, 0);
    }
#pragma unroll
    for (int q = 0; q < 4; ++q) {
      float a = tanhf(acc[q]);
      unsigned short h, m, lo; split3(a, h, m, lo);
      AFR[0][zoff + 8 * q] = h; AFR[1][zoff + 8 * q] = m; AFR[2][zoff + 8 * q] = lo;
    }
    __syncthreads();
    f32x4 acc2 = {b2c, b2c, b2c, b2c};
#pragma unroll
    for (int ks = 0; ks < 2; ++ks) {
      const int ro = ks ? ro1 : ro0, wo = ks ? wo1 : wo0;
      s8x8 ah = *(const s8x8*)&AFR[0][ro];
      s8x8 am = *(const s8x8*)&AFR[1][ro];
      s8x8 al = *(const s8x8*)&AFR[2][ro];
      s8x8 wm = *(const s8x8*)&W2M[wo];
      s8x8 wl = *(const s8x8*)&W2L[wo];
      acc2 = MFMA16(ah, w2h[ks], acc2, 0, 0, 0);
      acc2 = MFMA16(am, w2h[ks], acc2, 0, 0, 0);
      acc2 = MFMA16(al, w2h[ks], acc2, 0, 0, 0);
      acc2 = MFMA16(ah, wm, acc2, 0, 0, 0);
      acc2 = MFMA16(am, wm, acc2, 0, 0, 0);
      acc2 = MFMA16(ah, wl, acc2, 0, 0, 0);
    }
#pragma unroll
    for (int q = 0; q < 4; ++q) kout[q] = acc2[q];   // C-frag == owner layout
  };

  // ---- load y0, emit ys[0] ----
  const size_t gbase = (size_t)(row0 + m0) * DIM + n;
#pragma unroll
  for (int q = 0; q < 4; ++q) {
    y[q] = y0[gbase + (size_t)q * DIM];
    out[gbase + (size_t)q * DIM] = y[q];
  }

  EVAL(y, k1);   // FSAL seed

  float h = (vt[1] - vt[0]) * 0.1f;
  int sid = 0;

  for (int seg = 0; seg < TSTEPS - 1; ++seg) {
    const float t1 = vt[seg + 1];
    float t = vt[seg];

    for (int st = 0; st < MAXST; ++st) {
      float rem = t1 - t;
      if (!(rem > 1e-9f)) break;
      float htry = fminf(h, rem);

#pragma unroll
      for (int q = 0; q < 4; ++q) z[q] = fmaf(htry, C21 * k1[q], y[q]);
      EVAL(z, k2);
#pragma unroll
      for (int q = 0; q < 4; ++q) {
        float c = fmaf(C32, k2[q], C31 * k1[q]);
        z[q] = fmaf(htry, c, y[q]);
      }
      EVAL(z, k3);
#pragma unroll
      for (int q = 0; q < 4; ++q) {
        float c = C41 * k1[q]; c = fmaf(C42, k2[q], c); c = fmaf(C43, k3[q], c);
        z[q] = fmaf(htry, c, y[q]);
      }
      EVAL(z, k4);
#pragma unroll
      for (int q = 0; q < 4; ++q) {
        float c = C51 * k1[q]; c = fmaf(C52, k2[q], c); c = fmaf(C53, k3[q], c);
        c = fmaf(C54, k4[q], c);
        z[q] = fmaf(htry, c, y[q]);
      }
      EVAL(z, k5);
#pragma unroll
      for (int q = 0; q < 4; ++q) {
        float c = C61 * k1[q]; c = fmaf(C62, k2[q], c); c = fmaf(C63, k3[q], c);
        c = fmaf(C64, k4[q], c); c = fmaf(C65, k5[q], c);
        z[q] = fmaf(htry, c, y[q]);
      }
      EVAL(z, k6);
#pragma unroll
      for (int q = 0; q < 4; ++q) {
        float c = B1 * k1[q]; c = fmaf(B3, k3[q], c); c = fmaf(B4, k4[q], c);
        c = fmaf(B5, k5[q], c); c = fmaf(B6, k6[q], c);
        y5[q] = fmaf(htry, c, y[q]);
      }
      EVAL(y5, k7);

      float accq = 0.f;
#pragma unroll
      for (int q = 0; q < 4; ++q) {
        float e = E1 * k1[q]; e = fmaf(E3, k3[q], e); e = fmaf(E4, k4[q], e);
        e = fmaf(E5, k5[q], e); e = fmaf(E6, k6[q], e); e = fmaf(E7, k7[q], e);
        e *= htry;
        float sc = fmaf(ODE_RTOL, fmaxf(fabsf(y[q]), fabsf(y5[q])), ODE_ATOL);
        float qq = e / sc;
        accq = fmaf(qq, qq, accq);
      }

      // ---- deterministic global reduction + self-resetting grid barrier ----
#pragma unroll
      for (int off = 32; off; off >>= 1) accq += __shfl_xor(accq, off, 64);
      if (l == 0) redbuf[w] = accq;
      __syncthreads();
      if (tid == 0) {
        float bsum = 0.f;
#pragma unroll
        for (int i = 0; i < 8; ++i) bsum += redbuf[i];
        atomicExch(&g_part[sid * NBLK + (int)blockIdx.x], bsum);
        __threadfence();
        atomicAdd(&g_cnt[sid], 1u);
      }
      float tot;
      if (blockIdx.x == 0) {
        if (tid == 0) {
          while (atomicAdd(&g_cnt[sid], 0u) < (unsigned)NBLK)
            __builtin_amdgcn_s_sleep(2);
          __threadfence();
        }
        __syncthreads();
        float v = atomicAdd(&g_part[sid * NBLK + tid], 0.0f);  // 512 partials
#pragma unroll
        for (int off = 32; off; off >>= 1) v += __shfl_xor(v, off, 64);
        if (l == 0) redbuf[w] = v;
        __syncthreads();
        if (tid == 0) {
          float s = 0.f;
#pragma unroll
          for (int i = 0; i < 8; ++i) s += redbuf[i];
          atomicExch(&g_tot[sid], s);
          __threadfence();
          atomicExch(&g_flag[sid], 1u);
          bcast = s;
        }
        __syncthreads();
        tot = bcast;
      } else {
        if (tid == 0) {
          while (atomicAdd(&g_flag[sid], 0u) == 0u)
            __builtin_amdgcn_s_sleep(2);
          __threadfence();
          bcast = atomicAdd(&g_tot[sid], 0.0f);
        }
        __syncthreads();
        tot = bcast;
      }
      if (tid == 0) {   // last block through resets the slot to zero
        __threadfence();
        unsigned d = atomicAdd(&g_done[sid], 1u);
        if (d == (unsigned)(NBLK - 1)) {
          atomicExch(&g_cnt[sid], 0u);
          atomicExch(&g_flag[sid], 0u);
          atomicExch(&g_done[sid], 0u);
        }
      }

      float err_norm = fmaxf(sqrtf(tot * (1.0f / (float)(NROW * DIM))), 1e-10f);
      bool accept  = (err_norm <= 1.0f);
      float factor = fminf(fmaxf(0.9f * powf(err_norm, -0.2f), 0.2f), 10.0f);
      if (accept) {
        t = t + htry;
#pragma unroll
        for (int q = 0; q < 4; ++q) { y[q] = y5[q]; k1[q] = k7[q]; }  // FSAL
      }
      h = htry * factor;
      ++sid;
    }

#pragma unroll
    for (int q = 0; q < 4; ++q)
      out[((size_t)(seg + 1) * NROW) * DIM + gbase + (size_t)q * DIM] = y[q];
  }
}

extern "C" void kernel_launch(void* const* d_in, const int* in_sizes, int n_in,
                              void* d_out, int out_size, void* d_ws, size_t ws_size,
                              hipStream_t stream) {
  const float* vt = (const float*)d_in[0];
  const float* y0 = (const float*)d_in[1];
  const float* W1 = (const float*)d_in[2];
  const float* b1 = (const float*)d_in[3];
  const float* W2 = (const float*)d_in[4];
  const float* b2 = (const float*)d_in[5];
  float* out = (float*)d_out;
  (void)d_ws; (void)ws_size;

  hipLaunchKernelGGL(ode_dopri5_mfma, dim3(NBLK), dim3(TPB), 0, stream,
                     vt, y0, W1, b1, W2, b2, out);
}